// Round 10
// baseline (406.396 us; speedup 1.0000x reference)
//
#include <hip/hip_runtime.h>

typedef unsigned short ushort_t;
typedef unsigned int uint_t;
typedef __attribute__((ext_vector_type(8))) _Float16 f16x8;
typedef __attribute__((ext_vector_type(4))) float floatx4;

#define ZDIM 32
#define KDIM 4
#define HDIM 128
#define B_TOTAL 32768
#define TB 32

// ws layout (ushort element offsets): Wd fp16 [k][n][c], Wsm fp16 [m][n][c]
#define WS_WD16 0            // 4*1024*128 = 524288
#define WS_SM16 524288       // 3*128*128 = 49152

// LDS layout (byte offsets). D is fp16: [batch][i][j] at batch*1092 + i*34 + j
// (ushort units).
#define D_ROW   34
#define D_BP    1092
#define SH_D_OFF  0          // ushort[32][1092] = 69888 B
#define AUX_PITCH 132
#define SH_AUX_OFF 0         // float [3][32][132] = 50688 B (pre-loop, aliases D)
#define SH_H_OFF  50688      // half [32][136] = 8704 B (pre-loop, aliases D)
#define SH_Z_OFF  69888      // float [32][36] = 4608 B
#define SH_T_OFF  74496      // float [32][36] = 4608 B
#define LDS_BYTES 79104      // x2 = 158208 <= 160 KiB -> 2 WG/CU via LDS

__device__ __forceinline__ float fast_tanh(float x) {
    float e = __expf(2.0f * x);
    return 1.0f - 2.0f / (e + 1.0f);
}
__device__ __forceinline__ float f16lo(uint_t v) {
    return (float)__builtin_bit_cast(_Float16, (ushort_t)(v & 0xFFFFu));
}
__device__ __forceinline__ float f16hi(uint_t v) {
    return (float)__builtin_bit_cast(_Float16, (ushort_t)(v >> 16));
}
__device__ __forceinline__ ushort_t f2h(float x) {
    return __builtin_bit_cast(ushort_t, (_Float16)x);
}
__device__ __forceinline__ ushort4 cvt4(float4 v) {
    ushort4 o; o.x = f2h(v.x); o.y = f2h(v.y); o.z = f2h(v.z); o.w = f2h(v.w);
    return o;
}
// pack 4 floats into 2 dwords of fp16 (register-pressure relief; kk index
// folds at compile time under full unroll)
__device__ __forceinline__ uint2 packq(float4 v) {
    uint2 r;
    r.x = (uint_t)f2h(v.x) | ((uint_t)f2h(v.y) << 16);
    r.y = (uint_t)f2h(v.z) | ((uint_t)f2h(v.w) << 16);
    return r;
}
__device__ __forceinline__ float half_at(uint2 q, int kk) {
    uint_t w = (kk & 2) ? q.y : q.x;
    return (kk & 1) ? f16hi(w) : f16lo(w);
}

// ---------------------------------------------------------------------------
// Kernel 1: convert Wd (reordered per-k-slice) and Wd1/Wd2/Wb to fp16.
// ---------------------------------------------------------------------------
__global__ __launch_bounds__(256) void convert_kernel(
    const float* __restrict__ Wd, const float* __restrict__ Wd1,
    const float* __restrict__ Wd2, const float* __restrict__ Wb,
    ushort_t* __restrict__ ws)
{
    int g = blockIdx.x * 256 + threadIdx.x;
    if (g < 131072) {
        int k = g >> 15;            // 32768 float4 per k-slice
        int rem = g & 32767;
        int n = rem >> 5;           // n = i*32+j
        int c4 = rem & 31;
        float4 v = *((const float4*)Wd + (size_t)(4 * n + k) * 32 + c4);
        ((ushort4*)(ws + WS_WD16))[g] = cvt4(v);
    } else {
        int s = g - 131072;         // [0, 12288)
        const float* src = (s < 4096) ? Wd1 : ((s < 8192) ? Wd2 : Wb);
        int r = s & 4095;
        float4 v = ((const float4*)src)[r];
        ((ushort4*)(ws + WS_SM16))[s] = cvt4(v);
    }
}

// ---------------------------------------------------------------------------
// Kernel 2: fused fp16 encoder GEMMs + K-step flow.
// 512 threads, __launch_bounds__(512,4): 64 arch + 64 acc regs -> 2 WGs/CU
// (LDS 79 KB also caps at 2). GEMM processes one 16-col tile per iteration
// (16 iters x 4 b128 loads) to keep peak arch demand <= 64 (anti-spill).
// Round-10 change: reinstated the mid-flow __syncthreads() between the
// pre/tanh phase and the dz phase. Round 9 diverged intermittently on graph
// replay; the only unprotected cross-thread edge was the sh_t hand-off that
// relied on intra-wave lockstep ordering. Cost: 4 barriers/launch (~1%).
// ---------------------------------------------------------------------------
__global__ __launch_bounds__(512, 4) void sylv_kernel(
    const ushort_t* __restrict__ wsb,
    const float* __restrict__ hglob,
    const float* __restrict__ z0,
    const float* __restrict__ bd,
    const float* __restrict__ bd1,
    const float* __restrict__ bd2,
    const float* __restrict__ bb,
    float* __restrict__ out)
{
    extern __shared__ char smem[];
    _Float16* Dh     = (_Float16*)(smem + SH_D_OFF);
    float*    sh_aux = (float*)(smem + SH_AUX_OFF);
    _Float16* sh_h   = (_Float16*)(smem + SH_H_OFF);
    float*    sh_z   = (float*)(smem + SH_Z_OFF);
    float*    sh_t   = (float*)(smem + SH_T_OFF);

    const int t   = threadIdx.x;
    const int bg0 = blockIdx.x * TB;
    const int lane = t & 63, w = t >> 6;
    const int l15 = lane & 15, l4 = lane >> 4;
    const int rh = w & 1;           // row-half (batches rh*16 .. rh*16+15)
    const int cg = w >> 1;          // column group (256 cols each)
    // flow mapping: 16 contiguous lanes (one quarter-wave) own one batch fb.
    const int j2 = t & 15;
    const int bq = (t >> 4) & 3;
    const int fb = (w & 1) | (bq << 1) | ((w >> 1) << 3);

    // ---- stage h (fp32 -> fp16 in LDS) and z0 ----
    {
        const float4* hsrc = (const float4*)(hglob + (size_t)bg0 * HDIM);
        #pragma unroll
        for (int it = 0; it < 2; ++it) {
            int c = t + it * 512;       // 1024 float4 chunks
            int row = c >> 5, col4 = c & 31;
            float4 v = hsrc[c];
            *(ushort4*)((ushort_t*)sh_h + row * 136 + col4 * 4) = cvt4(v);
        }
        int zb = t >> 4, zc = t & 15;
        float2 zv = *(const float2*)(z0 + (size_t)(bg0 + zb) * ZDIM + zc * 2);
        *(float2*)(sh_z + zb * 36 + zc * 2) = zv;
    }
    __syncthreads();

    // ---- A fragments for THIS wave's row-half: A[m=lane&15][k=quad*8+j] ----
    f16x8 ah[4];
    #pragma unroll
    for (int kc = 0; kc < 4; ++kc)
        ah[kc] = *(const f16x8*)(sh_h + (rh * 16 + l15) * 136 + kc * 32 + l4 * 8);

    // ---- small GEMMs (fp16): d1, d2, bpre -> aux[m][batch][n] ----
    // 24 p-jobs x 2 rh-waves = 48; each wave does 6 for its rh.
    #pragma unroll
    for (int pi = 0; pi < 6; ++pi) {
        int p = cg * 6 + pi;            // [0,24)
        int m_i = p >> 3, nt = p & 7, n = nt * 16 + l15;
        const _Float16* wp = (const _Float16*)(wsb + WS_SM16) + (size_t)(m_i * 128 + n) * 128 + l4 * 8;
        floatx4 a0 = {0.f, 0.f, 0.f, 0.f};
        #pragma unroll
        for (int kc = 0; kc < 4; ++kc) {
            f16x8 bh = *(const f16x8*)(wp + kc * 32);
            a0 = __builtin_amdgcn_mfma_f32_16x16x32_f16(ah[kc], bh, a0, 0, 0, 0);
        }
        const float* bv = (m_i == 0) ? bd1 : ((m_i == 1) ? bd2 : bb);
        float bias = bv[n];
        float* ap = sh_aux + m_i * (32 * AUX_PITCH) + n;
        #pragma unroll
        for (int r = 0; r < 4; ++r) {
            float v0 = a0[r] + bias;
            if (m_i < 2) v0 = fast_tanh(v0);
            ap[(rh * 16 + l4 * 4 + r) * AUX_PITCH] = v0;
        }
    }
    __syncthreads();

    // ---- aux -> 12 packed-fp16 dwords/thread, then free the D region ----
    uint2 d1a = packq(*(const float4*)(sh_aux + 0 * (32 * AUX_PITCH) + fb * AUX_PITCH + j2 * 4));
    uint2 d2a = packq(*(const float4*)(sh_aux + 1 * (32 * AUX_PITCH) + fb * AUX_PITCH + j2 * 4));
    uint2 bpa = packq(*(const float4*)(sh_aux + 2 * (32 * AUX_PITCH) + fb * AUX_PITCH + j2 * 4));
    uint2 d1b = packq(*(const float4*)(sh_aux + 0 * (32 * AUX_PITCH) + fb * AUX_PITCH + (j2 + 16) * 4));
    uint2 d2b = packq(*(const float4*)(sh_aux + 1 * (32 * AUX_PITCH) + fb * AUX_PITCH + (j2 + 16) * 4));
    uint2 bpb = packq(*(const float4*)(sh_aux + 2 * (32 * AUX_PITCH) + fb * AUX_PITCH + (j2 + 16) * 4));
    __syncthreads();

    float ld_acc = 0.f;
    const _Float16* Db  = Dh + fb * D_BP;

    #pragma unroll
    for (int kk = 0; kk < KDIM; ++kk) {
        // ---- GEMM: D_k[b][n] = h@Wd_k^T + bd (fp16 inputs, fp32 acc) ----
        // One 16-col tile per iteration: low register footprint, no spill.
        const _Float16* wdk = (const _Float16*)(wsb + WS_WD16) + (size_t)kk * 131072;
        #pragma unroll
        for (int g = 0; g < 16; ++g) {
            int nc = cg * 256 + g * 16 + l15;
            const _Float16* w0 = wdk + (size_t)nc * 128 + l4 * 8;
            floatx4 a0 = {0.f,0.f,0.f,0.f};
            #pragma unroll
            for (int kc = 0; kc < 4; ++kc) {
                f16x8 b0 = *(const f16x8*)(w0 + kc * 32);
                a0 = __builtin_amdgcn_mfma_f32_16x16x32_f16(ah[kc], b0, a0, 0, 0, 0);
            }
            int ii = nc >> 5;
            int base = ii * D_ROW + (nc & 31);
            float bias0 = bd[4 * nc + kk];
            #pragma unroll
            for (int r = 0; r < 4; ++r)
                Dh[(rh * 16 + l4 * 4 + r) * D_BP + base] = (_Float16)(a0[r] + bias0);
        }
        __syncthreads();

        // ---- pre[j] = b[j] + z_per[j]*d2[j] + sum_{i>j} z_per[i]*D[i,j] ----
        const bool flip = (kk & 1) != 0;
        const int zj0 = flip ? (31 - j2) : j2;
        const int zj1 = flip ? (15 - j2) : (j2 + 16);
        float s0 = half_at(bpa, kk) + sh_z[fb * 36 + zj0] * half_at(d2a, kk);
        float s1 = half_at(bpb, kk) + sh_z[fb * 36 + zj1] * half_at(d2b, kk);
        #pragma unroll
        for (int i = 1; i <= 15; ++i) {       // masked vs j2
            float zi = sh_z[fb * 36 + (flip ? (31 - i) : i)];
            float dd = (float)Db[i * D_ROW + j2];
            s0 = fmaf(dd, (i > j2) ? zi : 0.f, s0);
        }
        #pragma unroll
        for (int i = 16; i < 32; ++i) {       // i > j2 always; s1 masked
            float zi = sh_z[fb * 36 + (flip ? (31 - i) : i)];
            s0 = fmaf((float)Db[i * D_ROW + j2], zi, s0);
            if (i >= 17)
                s1 = fmaf((float)Db[i * D_ROW + j2 + 16], (i > j2 + 16) ? zi : 0.f, s1);
        }
        float t0 = fast_tanh(s0), t1 = fast_tanh(s1);
        sh_t[fb * 36 + j2] = t0;
        sh_t[fb * 36 + j2 + 16] = t1;
        float dj0 = (1.f - t0 * t0) * (half_at(d1a, kk) * half_at(d2a, kk)) + 1.f;
        float dj1 = (1.f - t1 * t1) * (half_at(d1b, kk) * half_at(d2b, kk)) + 1.f;
        ld_acc += __logf(fabsf(dj0)) + __logf(fabsf(dj1));
        // Barrier reinstated (round-10): protects the sh_t hand-off without
        // relying on intra-wave lockstep DS ordering (round-9 flake suspect).
        __syncthreads();

        // ---- dz[p] = t[p]*d1[p] + sum_{j>p} t[j]*D[p,j]; z update ----
        float dz0 = t0 * half_at(d1a, kk);    // p = j2
        float dz1 = t1 * half_at(d1b, kk);    // p = j2+16
        const uint_t* r0 = (const uint_t*)Db + j2 * 17;     // D_ROW/2 words
        const uint_t* r1 = (const uint_t*)Db + (j2 + 16) * 17;
        #pragma unroll
        for (int w2 = 0; w2 < 8; ++w2) {      // j in [0,16): only dz0, masked
            uint_t v = r0[w2];
            int j0 = 2 * w2;
            float tl = sh_t[fb * 36 + j0];
            float th = sh_t[fb * 36 + j0 + 1];
            dz0 = fmaf(f16lo(v), (j0 > j2) ? tl : 0.f, dz0);
            dz0 = fmaf(f16hi(v), (j0 + 1 > j2) ? th : 0.f, dz0);
        }
        #pragma unroll
        for (int w2 = 8; w2 < 16; ++w2) {     // j in [16,32): dz0 unmasked, dz1 masked
            uint_t v0 = r0[w2];
            uint_t v1 = r1[w2];
            int j0 = 2 * w2;
            float tl = sh_t[fb * 36 + j0];
            float th = sh_t[fb * 36 + j0 + 1];
            dz0 = fmaf(f16lo(v0), tl, dz0);
            dz0 = fmaf(f16hi(v0), th, dz0);
            dz1 = fmaf(f16lo(v1), (j0 > j2 + 16) ? tl : 0.f, dz1);
            dz1 = fmaf(f16hi(v1), (j0 + 1 > j2 + 16) ? th : 0.f, dz1);
        }
        sh_z[fb * 36 + zj0] += dz0;
        sh_z[fb * 36 + zj1] += dz1;
        __syncthreads();
    }

    // ---- epilogue: write z and log_det_j ----
    {
        int zb = t >> 4, zc = t & 15;
        float2 zv = *(const float2*)(sh_z + zb * 36 + zc * 2);
        *(float2*)(out + (size_t)(bg0 + zb) * ZDIM + zc * 2) = zv;
        float v = ld_acc;
        v += __shfl_xor(v, 1, 16);
        v += __shfl_xor(v, 2, 16);
        v += __shfl_xor(v, 4, 16);
        v += __shfl_xor(v, 8, 16);
        if (j2 == 0) out[(size_t)B_TOTAL * ZDIM + bg0 + fb] = v;
    }
}

extern "C" void kernel_launch(void* const* d_in, const int* in_sizes, int n_in,
                              void* d_out, int out_size, void* d_ws, size_t ws_size,
                              hipStream_t stream) {
    const float* z0  = (const float*)d_in[0];
    const float* h   = (const float*)d_in[1];
    const float* Wd  = (const float*)d_in[2];
    const float* bd  = (const float*)d_in[3];
    const float* Wd1 = (const float*)d_in[4];
    const float* bd1 = (const float*)d_in[5];
    const float* Wd2 = (const float*)d_in[6];
    const float* bd2 = (const float*)d_in[7];
    const float* Wb  = (const float*)d_in[8];
    const float* bb  = (const float*)d_in[9];
    ushort_t* ws = (ushort_t*)d_ws;
    float* out = (float*)d_out;

    convert_kernel<<<560, 256, 0, stream>>>(Wd, Wd1, Wd2, Wb, ws);

    (void)hipFuncSetAttribute((const void*)sylv_kernel,
                              hipFuncAttributeMaxDynamicSharedMemorySize, LDS_BYTES);
    sylv_kernel<<<B_TOTAL / TB, 512, LDS_BYTES, stream>>>(ws, h, z0, bd, bd1, bd2, bb, out);
}

// Round 11
// 263.464 us; speedup vs baseline: 1.5425x; 1.5425x over previous
//
#include <hip/hip_runtime.h>

typedef unsigned short ushort_t;
typedef unsigned int uint_t;
typedef __attribute__((ext_vector_type(8))) _Float16 f16x8;
typedef __attribute__((ext_vector_type(4))) float floatx4;

#define ZDIM 32
#define KDIM 4
#define HDIM 128
#define B_TOTAL 32768
#define TB 64

// ws layout (ushort element offsets): Wd fp16 [k][n][c], Wsm fp16 [m][n][c]
#define WS_WD16 0            // 4*1024*128 = 524288
#define WS_SM16 524288       // 3*128*128 = 49152

// LDS layout (byte offsets). D fp16: [batch][i][j] at batch*1096 + i*34 + j
// (ushort units). Batch pitch 1096 => 548 words == 4 mod 32: flow reads
// (8 fb-groups x 4 j-words) tile all 32 banks -> conflict-free.
#define D_ROW   34
#define D_BP    1096
#define SH_D_OFF  0          // ushort[64][1096] = 140288 B
#define AUX_PITCH 132
#define SH_AUX_OFF 0         // float [3][64][132] = 101376 B (pre-loop, aliases D)
#define SH_H_OFF  101376     // half [64][136] = 17408 B (pre-loop, aliases D; end 118784)
#define SH_Z_OFF  140288     // float [64][36] = 9216 B
#define SH_T_OFF  149504     // float [64][36] = 9216 B
#define LDS_BYTES 158720     // 1 WG/CU (<= 160 KiB)

__device__ __forceinline__ float fast_tanh(float x) {
    float e = __expf(2.0f * x);
    return 1.0f - 2.0f / (e + 1.0f);
}
__device__ __forceinline__ float f16lo(uint_t v) {
    return (float)__builtin_bit_cast(_Float16, (ushort_t)(v & 0xFFFFu));
}
__device__ __forceinline__ float f16hi(uint_t v) {
    return (float)__builtin_bit_cast(_Float16, (ushort_t)(v >> 16));
}
__device__ __forceinline__ ushort_t f2h(float x) {
    return __builtin_bit_cast(ushort_t, (_Float16)x);
}
__device__ __forceinline__ ushort4 cvt4(float4 v) {
    ushort4 o; o.x = f2h(v.x); o.y = f2h(v.y); o.z = f2h(v.z); o.w = f2h(v.w);
    return o;
}
// pack 4 floats into 2 dwords of fp16 (kk folds at compile time under unroll)
__device__ __forceinline__ uint2 packq(float4 v) {
    uint2 r;
    r.x = (uint_t)f2h(v.x) | ((uint_t)f2h(v.y) << 16);
    r.y = (uint_t)f2h(v.z) | ((uint_t)f2h(v.w) << 16);
    return r;
}
__device__ __forceinline__ float half_at(uint2 q, int kk) {
    uint_t w = (kk & 2) ? q.y : q.x;
    return (kk & 1) ? f16hi(w) : f16lo(w);
}

// ---------------------------------------------------------------------------
// Kernel 1: convert Wd (reordered per-k-slice) and Wd1/Wd2/Wb to fp16.
// ---------------------------------------------------------------------------
__global__ __launch_bounds__(256) void convert_kernel(
    const float* __restrict__ Wd, const float* __restrict__ Wd1,
    const float* __restrict__ Wd2, const float* __restrict__ Wb,
    ushort_t* __restrict__ ws)
{
    int g = blockIdx.x * 256 + threadIdx.x;
    if (g < 131072) {
        int k = g >> 15;            // 32768 float4 per k-slice
        int rem = g & 32767;
        int n = rem >> 5;           // n = i*32+j
        int c4 = rem & 31;
        float4 v = *((const float4*)Wd + (size_t)(4 * n + k) * 32 + c4);
        ((ushort4*)(ws + WS_WD16))[g] = cvt4(v);
    } else {
        int s = g - 131072;         // [0, 12288)
        const float* src = (s < 4096) ? Wd1 : ((s < 8192) ? Wd2 : Wb);
        int r = s & 4095;
        float4 v = ((const float4*)src)[r];
        ((ushort4*)(ws + WS_SM16))[s] = cvt4(v);
    }
}

// ---------------------------------------------------------------------------
// Kernel 2: fused fp16 encoder GEMMs + K-step flow. TB=64 batches/WG.
// 512 threads, __launch_bounds__(512,2) -> 128 arch regs (NO spill; the
// (512,4)/64-reg family spilled 260-500 MB scratch in rounds 4-10).
// Each wave holds TWO 16-row A-tiles (rg = w&1 selects rows rg*32..+31),
// so every B-fragment load feeds 2 MFMAs; WG count halves to 512.
// Wd L2 traffic: 2 GB -> 1 GB; loads-per-MFMA halved (latency hiding).
// Flow: 8 threads/batch x 4 j's, round-2's verified mask logic.
// ---------------------------------------------------------------------------
__global__ __launch_bounds__(512, 2) void sylv_kernel(
    const ushort_t* __restrict__ wsb,
    const float* __restrict__ hglob,
    const float* __restrict__ z0,
    const float* __restrict__ bd,
    const float* __restrict__ bd1,
    const float* __restrict__ bd2,
    const float* __restrict__ bb,
    float* __restrict__ out)
{
    extern __shared__ char smem[];
    _Float16* Dh     = (_Float16*)(smem + SH_D_OFF);
    float*    sh_aux = (float*)(smem + SH_AUX_OFF);
    _Float16* sh_h   = (_Float16*)(smem + SH_H_OFF);
    float*    sh_z   = (float*)(smem + SH_Z_OFF);
    float*    sh_t   = (float*)(smem + SH_T_OFF);

    const int t   = threadIdx.x;
    const int bg0 = blockIdx.x * TB;
    const int lane = t & 63, w = t >> 6;
    const int l15 = lane & 15, l4 = lane >> 4;
    const int rg = w & 1;           // row-pair group: rows rg*32 .. rg*32+31
    const int cg = w >> 1;          // column group (256 cols each)
    // flow mapping: 8 threads per batch; thread handles j in {j3, j3+8, j3+16, j3+24}
    const int j3 = t & 7;
    const int fb = t >> 3;          // 0..63

    // ---- stage h (fp32 -> fp16 in LDS) and z0 ----
    {
        const float4* hsrc = (const float4*)(hglob + (size_t)bg0 * HDIM);
        #pragma unroll
        for (int it = 0; it < 4; ++it) {
            int c = t + it * 512;       // 2048 float4 chunks
            int row = c >> 5, col4 = c & 31;
            float4 v = hsrc[c];
            *(ushort4*)((ushort_t*)sh_h + row * 136 + col4 * 4) = cvt4(v);
        }
        float4 zv = *(const float4*)(z0 + (size_t)(bg0 + fb) * ZDIM + j3 * 4);
        *(float4*)(sh_z + fb * 36 + j3 * 4) = zv;
    }
    __syncthreads();

    // ---- A fragments: TWO 16-row tiles for this wave's row-pair group ----
    f16x8 ah[2][4];
    #pragma unroll
    for (int mt = 0; mt < 2; ++mt)
        #pragma unroll
        for (int kc = 0; kc < 4; ++kc)
            ah[mt][kc] = *(const f16x8*)(sh_h + (rg * 32 + mt * 16 + l15) * 136 + kc * 32 + l4 * 8);

    // ---- small GEMMs (fp16): d1, d2, bpre -> aux[m][batch][n] ----
    // 24 (m,ntile) jobs over 4 col-groups; each wave does both its row-tiles.
    #pragma unroll
    for (int pi = 0; pi < 6; ++pi) {
        int p = cg * 6 + pi;            // [0,24)
        int m_i = p >> 3, nt = p & 7, n = nt * 16 + l15;
        const _Float16* wp = (const _Float16*)(wsb + WS_SM16) + (size_t)(m_i * 128 + n) * 128 + l4 * 8;
        floatx4 a0 = {0.f, 0.f, 0.f, 0.f}, a1 = {0.f, 0.f, 0.f, 0.f};
        #pragma unroll
        for (int kc = 0; kc < 4; ++kc) {
            f16x8 bh = *(const f16x8*)(wp + kc * 32);
            a0 = __builtin_amdgcn_mfma_f32_16x16x32_f16(ah[0][kc], bh, a0, 0, 0, 0);
            a1 = __builtin_amdgcn_mfma_f32_16x16x32_f16(ah[1][kc], bh, a1, 0, 0, 0);
        }
        const float* bv = (m_i == 0) ? bd1 : ((m_i == 1) ? bd2 : bb);
        float bias = bv[n];
        float* ap = sh_aux + m_i * (64 * AUX_PITCH) + n;
        #pragma unroll
        for (int r = 0; r < 4; ++r) {
            float v0 = a0[r] + bias, v1 = a1[r] + bias;
            if (m_i < 2) { v0 = fast_tanh(v0); v1 = fast_tanh(v1); }
            ap[(rg * 32 + l4 * 4 + r) * AUX_PITCH] = v0;
            ap[(rg * 32 + 16 + l4 * 4 + r) * AUX_PITCH] = v1;
        }
    }
    __syncthreads();

    // ---- aux -> 24 packed-fp16 dwords/thread, then free the D region ----
    uint2 d1q[4], d2q[4], bpq[4];
    #pragma unroll
    for (int q = 0; q < 4; ++q) {
        int joff = (j3 + 8 * q) * 4;
        d1q[q] = packq(*(const float4*)(sh_aux + 0 * (64 * AUX_PITCH) + fb * AUX_PITCH + joff));
        d2q[q] = packq(*(const float4*)(sh_aux + 1 * (64 * AUX_PITCH) + fb * AUX_PITCH + joff));
        bpq[q] = packq(*(const float4*)(sh_aux + 2 * (64 * AUX_PITCH) + fb * AUX_PITCH + joff));
    }
    __syncthreads();

    float ld_acc = 0.f;
    const _Float16* Db  = Dh + fb * D_BP;       // this thread's batch row
    const _Float16* Dbp = Db + j3;              // pre-phase base (imm offsets)
    const uint_t*   Dbw = (const uint_t*)Db + j3 * 17;  // dz-phase base

    #pragma unroll
    for (int kk = 0; kk < KDIM; ++kk) {
        // ---- GEMM: D_k[b][n] = h@Wd_k^T + bd (fp16 in, fp32 acc) ----
        const _Float16* wdk = (const _Float16*)(wsb + WS_WD16) + (size_t)kk * 131072;
        #pragma unroll
        for (int g = 0; g < 16; ++g) {
            int nc = cg * 256 + g * 16 + l15;
            const _Float16* w0 = wdk + (size_t)nc * 128 + l4 * 8;
            floatx4 a0 = {0.f,0.f,0.f,0.f}, a1 = {0.f,0.f,0.f,0.f};
            #pragma unroll
            for (int kc = 0; kc < 4; ++kc) {
                f16x8 b0 = *(const f16x8*)(w0 + kc * 32);
                a0 = __builtin_amdgcn_mfma_f32_16x16x32_f16(ah[0][kc], b0, a0, 0, 0, 0);
                a1 = __builtin_amdgcn_mfma_f32_16x16x32_f16(ah[1][kc], b0, a1, 0, 0, 0);
            }
            int ii = nc >> 5;
            int base = ii * D_ROW + (nc & 31);
            float bias0 = bd[4 * nc + kk];
            #pragma unroll
            for (int r = 0; r < 4; ++r) {
                Dh[(rg * 32 + l4 * 4 + r) * D_BP + base]      = (_Float16)(a0[r] + bias0);
                Dh[(rg * 32 + 16 + l4 * 4 + r) * D_BP + base] = (_Float16)(a1[r] + bias0);
            }
        }
        __syncthreads();

        // ---- pre[j] = b[j] + z_per[j]*d2[j] + sum_{i>j} z_per[i]*D[i,j] ----
        const bool flip = (kk & 1) != 0;
        float s[4];
        #pragma unroll
        for (int q = 0; q < 4; ++q) {
            int j = j3 + 8 * q;
            int zidx = flip ? (31 - j) : j;
            s[q] = half_at(bpq[q], kk) + sh_z[fb * 36 + zidx] * half_at(d2q[q], kk);
        }
        #pragma unroll
        for (int i = 1; i < 32; ++i) {
            float zi = sh_z[fb * 36 + (flip ? (31 - i) : i)];
            #pragma unroll
            for (int q = 0; q < 4; ++q) {
                if (i > 8 * q) {        // j = j3+8q >= 8q: i <= 8q never contributes
                    float dd = (float)Dbp[i * D_ROW + 8 * q];
                    float m = (i >= 8 * q + 8) ? zi : ((i > j3 + 8 * q) ? zi : 0.0f);
                    s[q] = fmaf(dd, m, s[q]);
                }
            }
        }
        float tq[4];
        #pragma unroll
        for (int q = 0; q < 4; ++q) {
            int j = j3 + 8 * q;
            float tt = fast_tanh(s[q]);
            tq[q] = tt;
            sh_t[fb * 36 + j] = tt;
            float d1 = half_at(d1q[q], kk), d2 = half_at(d2q[q], kk);
            float dj = (1.f - tt * tt) * (d1 * d2) + 1.f;
            ld_acc += __logf(fabsf(dj));
        }
        // barrier protects the sh_t hand-off (round-9 flake lesson)
        __syncthreads();

        // ---- dz[p] = t[p]*d1[p] + sum_{j>p} t[j]*D[p,j]; z update ----
        float dzv[4];
        #pragma unroll
        for (int q = 0; q < 4; ++q)
            dzv[q] = tq[q] * half_at(d1q[q], kk);
        #pragma unroll
        for (int w2 = 0; w2 < 16; ++w2) {
            int j0 = 2 * w2;
            float tl = sh_t[fb * 36 + j0];
            float th = sh_t[fb * 36 + j0 + 1];
            #pragma unroll
            for (int q = 0; q < 4; ++q) {
                if (w2 >= 4 * q) {              // j <= 8q-1 < p never contributes
                    uint_t v = Dbw[136 * q + w2];   // row (j3+8q), word w2
                    if (w2 >= 4 * q + 4) {      // all j >= 8q+8 > p
                        dzv[q] = fmaf(f16lo(v), tl, dzv[q]);
                        dzv[q] = fmaf(f16hi(v), th, dzv[q]);
                    } else {
                        dzv[q] = fmaf(f16lo(v), (j0 > j3 + 8 * q) ? tl : 0.f, dzv[q]);
                        dzv[q] = fmaf(f16hi(v), (j0 + 1 > j3 + 8 * q) ? th : 0.f, dzv[q]);
                    }
                }
            }
        }
        #pragma unroll
        for (int q = 0; q < 4; ++q) {
            int j = j3 + 8 * q;
            int zidx = flip ? (31 - j) : j;
            sh_z[fb * 36 + zidx] += dzv[q];
        }
        __syncthreads();
    }

    // ---- epilogue: write z and log_det_j ----
    {
        float4 zv = *(const float4*)(sh_z + fb * 36 + j3 * 4);
        *(float4*)(out + (size_t)(bg0 + fb) * ZDIM + j3 * 4) = zv;
        float v = ld_acc;
        v += __shfl_xor(v, 1, 8);
        v += __shfl_xor(v, 2, 8);
        v += __shfl_xor(v, 4, 8);
        if (j3 == 0) out[(size_t)B_TOTAL * ZDIM + bg0 + fb] = v;
    }
}

extern "C" void kernel_launch(void* const* d_in, const int* in_sizes, int n_in,
                              void* d_out, int out_size, void* d_ws, size_t ws_size,
                              hipStream_t stream) {
    const float* z0  = (const float*)d_in[0];
    const float* h   = (const float*)d_in[1];
    const float* Wd  = (const float*)d_in[2];
    const float* bd  = (const float*)d_in[3];
    const float* Wd1 = (const float*)d_in[4];
    const float* bd1 = (const float*)d_in[5];
    const float* Wd2 = (const float*)d_in[6];
    const float* bd2 = (const float*)d_in[7];
    const float* Wb  = (const float*)d_in[8];
    const float* bb  = (const float*)d_in[9];
    ushort_t* ws = (ushort_t*)d_ws;
    float* out = (float*)d_out;

    convert_kernel<<<560, 256, 0, stream>>>(Wd, Wd1, Wd2, Wb, ws);

    (void)hipFuncSetAttribute((const void*)sylv_kernel,
                              hipFuncAttributeMaxDynamicSharedMemorySize, LDS_BYTES);
    sylv_kernel<<<B_TOTAL / TB, 512, LDS_BYTES, stream>>>(ws, h, z0, bd, bd1, bd2, bb, out);
}

// Round 12
// 263.376 us; speedup vs baseline: 1.5430x; 1.0003x over previous
//
#include <hip/hip_runtime.h>

typedef unsigned short ushort_t;
typedef unsigned int uint_t;
typedef __attribute__((ext_vector_type(8))) _Float16 f16x8;
typedef __attribute__((ext_vector_type(4))) float floatx4;

#define ZDIM 32
#define KDIM 4
#define HDIM 128
#define B_TOTAL 32768
#define TB 32

// ws layout (ushort element offsets): Wd fp16 [k][n][c], Wsm fp16 [m][n][c]
#define WS_WD16 0            // 4*1024*128 = 524288
#define WS_SM16 524288       // 3*128*128 = 49152

// LDS layout (byte offsets). D fp16: [batch][i][j] at batch*1096 + i*34 + j
// (ushort units). Batch pitch 1096 => 548 words == 4 mod 32: flow reads
// (8 fb-groups/wave x 4 words) tile all 32 banks -> conflict-free.
#define D_ROW   34
#define D_BP    1096
#define SH_D_OFF  0          // ushort[32][1096] = 70144 B
#define AUX_PITCH 132
#define SH_AUX_OFF 0         // float [3][32][132] = 50688 B (pre-loop, aliases D)
#define SH_H_OFF  50688      // half [32][136] = 8704 B (pre-loop, aliases D; end 59392)
#define SH_Z_OFF  70144      // float [32][36] = 4608 B
#define SH_T_OFF  74752      // float [32][36] = 4608 B
#define LDS_BYTES 79360      // x2 = 158720 <= 160 KiB -> 2 WGs/CU

__device__ __forceinline__ float fast_tanh(float x) {
    float e = __expf(2.0f * x);
    return 1.0f - 2.0f / (e + 1.0f);
}
__device__ __forceinline__ float f16lo(uint_t v) {
    return (float)__builtin_bit_cast(_Float16, (ushort_t)(v & 0xFFFFu));
}
__device__ __forceinline__ float f16hi(uint_t v) {
    return (float)__builtin_bit_cast(_Float16, (ushort_t)(v >> 16));
}
__device__ __forceinline__ ushort_t f2h(float x) {
    return __builtin_bit_cast(ushort_t, (_Float16)x);
}
__device__ __forceinline__ ushort4 cvt4(float4 v) {
    ushort4 o; o.x = f2h(v.x); o.y = f2h(v.y); o.z = f2h(v.z); o.w = f2h(v.w);
    return o;
}
// pack 4 floats into 2 dwords of fp16 (kk folds at compile time under unroll)
__device__ __forceinline__ uint2 packq(float4 v) {
    uint2 r;
    r.x = (uint_t)f2h(v.x) | ((uint_t)f2h(v.y) << 16);
    r.y = (uint_t)f2h(v.z) | ((uint_t)f2h(v.w) << 16);
    return r;
}
__device__ __forceinline__ float half_at(uint2 q, int kk) {
    uint_t w = (kk & 2) ? q.y : q.x;
    return (kk & 1) ? f16hi(w) : f16lo(w);
}

// ---------------------------------------------------------------------------
// Kernel 1: convert Wd (reordered per-k-slice) and Wd1/Wd2/Wb to fp16.
// ---------------------------------------------------------------------------
__global__ __launch_bounds__(256) void convert_kernel(
    const float* __restrict__ Wd, const float* __restrict__ Wd1,
    const float* __restrict__ Wd2, const float* __restrict__ Wb,
    ushort_t* __restrict__ ws)
{
    int g = blockIdx.x * 256 + threadIdx.x;
    if (g < 131072) {
        int k = g >> 15;            // 32768 float4 per k-slice
        int rem = g & 32767;
        int n = rem >> 5;           // n = i*32+j
        int c4 = rem & 31;
        float4 v = *((const float4*)Wd + (size_t)(4 * n + k) * 32 + c4);
        ((ushort4*)(ws + WS_WD16))[g] = cvt4(v);
    } else {
        int s = g - 131072;         // [0, 12288)
        const float* src = (s < 4096) ? Wd1 : ((s < 8192) ? Wd2 : Wb);
        int r = s & 4095;
        float4 v = ((const float4*)src)[r];
        ((ushort4*)(ws + WS_SM16))[s] = cvt4(v);
    }
}

// ---------------------------------------------------------------------------
// Kernel 2: fused fp16 encoder GEMMs + K-step flow. TB=32 batches/WG,
// 256 threads (4 waves), __launch_bounds__(256,2) -> 128 arch regs (no
// spill; proven budget from rounds 3/6/11) AND 2 WGs/CU (LDS 79.4 KB x 2
// fits 160 KiB). Round-12 change vs round 11: same total work repartitioned
// into half-size WGs so two independent WGs co-reside per CU -- one WG's
// flow phase (LDS+VALU) overlaps the other's GEMM phase (MFMA+L2), which a
// single barrier-serialized WG cannot do (m114 co-scheduling).
// Each wave holds TWO 16-row A-tiles (rows 0-31); 4 waves x 256 cols cover
// the 1024-col k-slice exactly (no duplicate B reads).
// ---------------------------------------------------------------------------
__global__ __launch_bounds__(256, 2) void sylv_kernel(
    const ushort_t* __restrict__ wsb,
    const float* __restrict__ hglob,
    const float* __restrict__ z0,
    const float* __restrict__ bd,
    const float* __restrict__ bd1,
    const float* __restrict__ bd2,
    const float* __restrict__ bb,
    float* __restrict__ out)
{
    extern __shared__ char smem[];
    _Float16* Dh     = (_Float16*)(smem + SH_D_OFF);
    float*    sh_aux = (float*)(smem + SH_AUX_OFF);
    _Float16* sh_h   = (_Float16*)(smem + SH_H_OFF);
    float*    sh_z   = (float*)(smem + SH_Z_OFF);
    float*    sh_t   = (float*)(smem + SH_T_OFF);

    const int t   = threadIdx.x;
    const int bg0 = blockIdx.x * TB;
    const int lane = t & 63, w = t >> 6;    // w = 0..3 = column group
    const int l15 = lane & 15, l4 = lane >> 4;
    // flow mapping: 8 threads per batch; thread handles j in {j3, j3+8, j3+16, j3+24}
    const int j3 = t & 7;
    const int fb = t >> 3;          // 0..31

    // ---- stage h (fp32 -> fp16 in LDS) and z0 ----
    {
        const float4* hsrc = (const float4*)(hglob + (size_t)bg0 * HDIM);
        #pragma unroll
        for (int it = 0; it < 4; ++it) {
            int c = t + it * 256;       // 1024 float4 chunks
            int row = c >> 5, col4 = c & 31;
            float4 v = hsrc[c];
            *(ushort4*)((ushort_t*)sh_h + row * 136 + col4 * 4) = cvt4(v);
        }
        float4 zv = *(const float4*)(z0 + (size_t)(bg0 + fb) * ZDIM + j3 * 4);
        *(float4*)(sh_z + fb * 36 + j3 * 4) = zv;
    }
    __syncthreads();

    // ---- A fragments: TWO 16-row tiles (rows 0..31), same for all waves ----
    f16x8 ah[2][4];
    #pragma unroll
    for (int mt = 0; mt < 2; ++mt)
        #pragma unroll
        for (int kc = 0; kc < 4; ++kc)
            ah[mt][kc] = *(const f16x8*)(sh_h + (mt * 16 + l15) * 136 + kc * 32 + l4 * 8);

    // ---- small GEMMs (fp16): d1, d2, bpre -> aux[m][batch][n] ----
    // 24 (m,ntile) jobs over 4 waves; each wave does both row-tiles.
    #pragma unroll
    for (int pi = 0; pi < 6; ++pi) {
        int p = w * 6 + pi;             // [0,24)
        int m_i = p >> 3, nt = p & 7, n = nt * 16 + l15;
        const _Float16* wp = (const _Float16*)(wsb + WS_SM16) + (size_t)(m_i * 128 + n) * 128 + l4 * 8;
        floatx4 a0 = {0.f, 0.f, 0.f, 0.f}, a1 = {0.f, 0.f, 0.f, 0.f};
        #pragma unroll
        for (int kc = 0; kc < 4; ++kc) {
            f16x8 bh = *(const f16x8*)(wp + kc * 32);
            a0 = __builtin_amdgcn_mfma_f32_16x16x32_f16(ah[0][kc], bh, a0, 0, 0, 0);
            a1 = __builtin_amdgcn_mfma_f32_16x16x32_f16(ah[1][kc], bh, a1, 0, 0, 0);
        }
        const float* bv = (m_i == 0) ? bd1 : ((m_i == 1) ? bd2 : bb);
        float bias = bv[n];
        float* ap = sh_aux + m_i * (32 * AUX_PITCH) + n;
        #pragma unroll
        for (int r = 0; r < 4; ++r) {
            float v0 = a0[r] + bias, v1 = a1[r] + bias;
            if (m_i < 2) { v0 = fast_tanh(v0); v1 = fast_tanh(v1); }
            ap[(l4 * 4 + r) * AUX_PITCH] = v0;
            ap[(16 + l4 * 4 + r) * AUX_PITCH] = v1;
        }
    }
    __syncthreads();

    // ---- aux -> 24 packed-fp16 dwords/thread, then free the D region ----
    uint2 d1q[4], d2q[4], bpq[4];
    #pragma unroll
    for (int q = 0; q < 4; ++q) {
        int joff = (j3 + 8 * q) * 4;
        d1q[q] = packq(*(const float4*)(sh_aux + 0 * (32 * AUX_PITCH) + fb * AUX_PITCH + joff));
        d2q[q] = packq(*(const float4*)(sh_aux + 1 * (32 * AUX_PITCH) + fb * AUX_PITCH + joff));
        bpq[q] = packq(*(const float4*)(sh_aux + 2 * (32 * AUX_PITCH) + fb * AUX_PITCH + joff));
    }
    __syncthreads();

    float ld_acc = 0.f;
    const _Float16* Db  = Dh + fb * D_BP;       // this thread's batch row
    const _Float16* Dbp = Db + j3;              // pre-phase base (imm offsets)
    const uint_t*   Dbw = (const uint_t*)Db + j3 * 17;  // dz-phase base

    #pragma unroll
    for (int kk = 0; kk < KDIM; ++kk) {
        // ---- GEMM: D_k[b][n] = h@Wd_k^T + bd (fp16 in, fp32 acc) ----
        const _Float16* wdk = (const _Float16*)(wsb + WS_WD16) + (size_t)kk * 131072;
        #pragma unroll
        for (int g = 0; g < 16; ++g) {
            int nc = w * 256 + g * 16 + l15;
            const _Float16* w0 = wdk + (size_t)nc * 128 + l4 * 8;
            floatx4 a0 = {0.f,0.f,0.f,0.f}, a1 = {0.f,0.f,0.f,0.f};
            #pragma unroll
            for (int kc = 0; kc < 4; ++kc) {
                f16x8 b0 = *(const f16x8*)(w0 + kc * 32);
                a0 = __builtin_amdgcn_mfma_f32_16x16x32_f16(ah[0][kc], b0, a0, 0, 0, 0);
                a1 = __builtin_amdgcn_mfma_f32_16x16x32_f16(ah[1][kc], b0, a1, 0, 0, 0);
            }
            int ii = nc >> 5;
            int base = ii * D_ROW + (nc & 31);
            float bias0 = bd[4 * nc + kk];
            #pragma unroll
            for (int r = 0; r < 4; ++r) {
                Dh[(l4 * 4 + r) * D_BP + base]      = (_Float16)(a0[r] + bias0);
                Dh[(16 + l4 * 4 + r) * D_BP + base] = (_Float16)(a1[r] + bias0);
            }
        }
        __syncthreads();

        // ---- pre[j] = b[j] + z_per[j]*d2[j] + sum_{i>j} z_per[i]*D[i,j] ----
        const bool flip = (kk & 1) != 0;
        float s[4];
        #pragma unroll
        for (int q = 0; q < 4; ++q) {
            int j = j3 + 8 * q;
            int zidx = flip ? (31 - j) : j;
            s[q] = half_at(bpq[q], kk) + sh_z[fb * 36 + zidx] * half_at(d2q[q], kk);
        }
        #pragma unroll
        for (int i = 1; i < 32; ++i) {
            float zi = sh_z[fb * 36 + (flip ? (31 - i) : i)];
            #pragma unroll
            for (int q = 0; q < 4; ++q) {
                if (i > 8 * q) {        // j = j3+8q >= 8q: i <= 8q never contributes
                    float dd = (float)Dbp[i * D_ROW + 8 * q];
                    float m = (i >= 8 * q + 8) ? zi : ((i > j3 + 8 * q) ? zi : 0.0f);
                    s[q] = fmaf(dd, m, s[q]);
                }
            }
        }
        float tq[4];
        #pragma unroll
        for (int q = 0; q < 4; ++q) {
            int j = j3 + 8 * q;
            float tt = fast_tanh(s[q]);
            tq[q] = tt;
            sh_t[fb * 36 + j] = tt;
            float d1 = half_at(d1q[q], kk), d2 = half_at(d2q[q], kk);
            float dj = (1.f - tt * tt) * (d1 * d2) + 1.f;
            ld_acc += __logf(fabsf(dj));
        }
        // barrier protects the sh_t hand-off (round-9 flake lesson)
        __syncthreads();

        // ---- dz[p] = t[p]*d1[p] + sum_{j>p} t[j]*D[p,j]; z update ----
        float dzv[4];
        #pragma unroll
        for (int q = 0; q < 4; ++q)
            dzv[q] = tq[q] * half_at(d1q[q], kk);
        #pragma unroll
        for (int w2 = 0; w2 < 16; ++w2) {
            int j0 = 2 * w2;
            float tl = sh_t[fb * 36 + j0];
            float th = sh_t[fb * 36 + j0 + 1];
            #pragma unroll
            for (int q = 0; q < 4; ++q) {
                if (w2 >= 4 * q) {              // j <= 8q-1 < p never contributes
                    uint_t v = Dbw[136 * q + w2];   // row (j3+8q), word w2
                    if (w2 >= 4 * q + 4) {      // all j >= 8q+8 > p
                        dzv[q] = fmaf(f16lo(v), tl, dzv[q]);
                        dzv[q] = fmaf(f16hi(v), th, dzv[q]);
                    } else {
                        dzv[q] = fmaf(f16lo(v), (j0 > j3 + 8 * q) ? tl : 0.f, dzv[q]);
                        dzv[q] = fmaf(f16hi(v), (j0 + 1 > j3 + 8 * q) ? th : 0.f, dzv[q]);
                    }
                }
            }
        }
        #pragma unroll
        for (int q = 0; q < 4; ++q) {
            int j = j3 + 8 * q;
            int zidx = flip ? (31 - j) : j;
            sh_z[fb * 36 + zidx] += dzv[q];
        }
        __syncthreads();
    }

    // ---- epilogue: write z and log_det_j ----
    {
        float4 zv = *(const float4*)(sh_z + fb * 36 + j3 * 4);
        *(float4*)(out + (size_t)(bg0 + fb) * ZDIM + j3 * 4) = zv;
        float v = ld_acc;
        v += __shfl_xor(v, 1, 8);
        v += __shfl_xor(v, 2, 8);
        v += __shfl_xor(v, 4, 8);
        if (j3 == 0) out[(size_t)B_TOTAL * ZDIM + bg0 + fb] = v;
    }
}

extern "C" void kernel_launch(void* const* d_in, const int* in_sizes, int n_in,
                              void* d_out, int out_size, void* d_ws, size_t ws_size,
                              hipStream_t stream) {
    const float* z0  = (const float*)d_in[0];
    const float* h   = (const float*)d_in[1];
    const float* Wd  = (const float*)d_in[2];
    const float* bd  = (const float*)d_in[3];
    const float* Wd1 = (const float*)d_in[4];
    const float* bd1 = (const float*)d_in[5];
    const float* Wd2 = (const float*)d_in[6];
    const float* bd2 = (const float*)d_in[7];
    const float* Wb  = (const float*)d_in[8];
    const float* bb  = (const float*)d_in[9];
    ushort_t* ws = (ushort_t*)d_ws;
    float* out = (float*)d_out;

    convert_kernel<<<560, 256, 0, stream>>>(Wd, Wd1, Wd2, Wb, ws);

    (void)hipFuncSetAttribute((const void*)sylv_kernel,
                              hipFuncAttributeMaxDynamicSharedMemorySize, LDS_BYTES);
    sylv_kernel<<<B_TOTAL / TB, 256, LDS_BYTES, stream>>>(ws, h, z0, bd, bd1, bd2, bb, out);
}